// Round 4
// baseline (1641.805 us; speedup 1.0000x reference)
//
#include <hip/hip_runtime.h>
#include <hip/hip_bf16.h>
#include <stdint.h>

// Problem: B=64, T=128, F=16, H=512, S=2.  All inputs fp32, lengths int32, out fp32 [64][14].
//
// R1: fixed half-staged h_l (NaN). R2: 1338us baseline. R3: relaxed poll (no per-iter L2 inv) -> 831us.
// R4 restructure of lstmk (was 635us, 4.96us/step, MfmaUtil 2.1%, 2.65e7 LDS conflict cycles):
//   - N-tile remap: wave w owns units w*8..w*8+7, tile0=[i,f] tile1=[g,o] -> cell update via
//     shfl_xor(8) register exchange; gates_l LDS + sync A eliminated.
//   - G_temb + bias load directly into MFMA accumulator C-layout (8x 2B cached loads/lane);
//     gbuf LDS (16-way bank conflicts) eliminated.
//   - xf@Wc folded into MFMA K-extension (K=512->544, cols 512..519 = xf bf16, Wc as
//     register-resident B-fragment); 128 scalar LDS-read FMAs/thread/step eliminated.
//   - Per-wave flags (64 per row-group, one per lane): wave release-stores its flag after its
//     own vmcnt drain; sync B barrier eliminated. One __syncthreads/step remains (stage->MFMA).
//   WAR safety: staging step t+1 into h_l requires poll(t+1) success, which requires every wave
//   of the row-group (incl. this block's) to have flagged t+1, which happens only after those
//   waves finished reading h_l for step t.
//
// Reshape quirk (faithful to torch): segment s', step t' uses source timestep n_t=(s'*128+t')>>1
// and embedding branch n_s=(s'*128+t')&1.

typedef __attribute__((ext_vector_type(8))) short bf16x8_t;
typedef __attribute__((ext_vector_type(4))) float f32x4_t;

// ---------------- workspace layout (bytes) ----------------
#define OFF_G      0u                      // bf16 [8192][2048]   33,554,432
#define OFF_TEMB   33554432u               // bf16 [8192][1024]   16,777,216
#define OFF_HH     50331648u               // bf16 [129][128][512] 16,908,288
#define OFF_WHH    67239936u               // bf16 [2048][512]     2,097,152
#define OFF_WMID   69337088u               // bf16 [2048][1024]    4,194,304
#define OFF_WC0    73531392u               // f32  [2048][8]          65,536
#define OFF_WC1    73596928u               // f32  [2048][8] (6 used) 65,536
#define OFF_BC     73662464u               // f32  [2][2048]          16,384
#define OFF_HFIN   73678848u               // f32  [64][1024]        262,144
#define OFF_FLAGS  73940992u               // u32  [129][8][64]      264,192
// total ~74.2 MB

__device__ __forceinline__ float bf2f(uint16_t u){
  union { uint32_t i; float f; } v; v.i = ((uint32_t)u) << 16; return v.f;
}
__device__ __forceinline__ uint16_t f2b(float f){
  union { float f; uint32_t i; } v; v.f = f;
  uint32_t r = v.i + 0x7fffu + ((v.i >> 16) & 1u);  // RNE
  return (uint16_t)(r >> 16);
}
__device__ __forceinline__ float sigm(float x){ return 1.0f/(1.0f + __expf(-x)); }
__device__ __forceinline__ float tanh_(float x){
  float xc = fminf(fmaxf(x, -15.f), 15.f);
  float t = __expf(2.f*xc);
  return (t - 1.f)/(t + 1.f);
}

// ---------------- prep1: weight folding + bf16 casts ----------------
__global__ void prep1(const float* __restrict__ W_ih, const float* __restrict__ W_hh,
                      const float* __restrict__ W_is0, const float* __restrict__ b_is0,
                      const float* __restrict__ W_is1, const float* __restrict__ b_is1,
                      const float* __restrict__ b_ih, const float* __restrict__ b_hh,
                      uint16_t* __restrict__ whh_b, uint16_t* __restrict__ wmid_b,
                      float* __restrict__ wc0, float* __restrict__ wc1, float* __restrict__ bc){
  const int n = blockIdx.x;        // gate column 0..2047
  const int tid = threadIdx.x;     // 256
  __shared__ float wrow[512];
  wrow[tid]       = W_ih[(size_t)n*1536 + tid];
  wrow[tid + 256] = W_ih[(size_t)n*1536 + 256 + tid];
  for (int j = tid; j < 1024; j += 256)
    wmid_b[(size_t)n*1024 + j] = f2b(W_ih[(size_t)n*1536 + 512 + j]);
  for (int k = tid; k < 512; k += 256)
    whh_b[(size_t)n*512 + k] = f2b(W_hh[(size_t)n*512 + k]);
  __syncthreads();
  if (tid < 8){
    float s = 0.f;
    for (int k = 0; k < 512; ++k) s += wrow[k]*W_is0[k*8 + tid];
    wc0[n*8 + tid] = s;
  } else if (tid < 16){
    int c = tid - 8;
    float s = 0.f;
    if (c < 6){ for (int k = 0; k < 512; ++k) s += wrow[k]*W_is1[k*6 + c]; }
    wc1[n*8 + c] = s;              // c==6,7 stay 0 (stride-8 padding)
  } else if (tid == 16){
    float s = b_ih[n] + b_hh[n];
    for (int k = 0; k < 512; ++k) s += wrow[k]*b_is0[k];
    bc[n] = s;
  } else if (tid == 17){
    float s = b_ih[n] + b_hh[n];
    for (int k = 0; k < 512; ++k) s += wrow[k]*b_is1[k];
    bc[2048 + n] = s;
  }
}

// ---------------- prep2: h_hist[0] + flag re-init (ws is poisoned each launch!) ----------------
__global__ void prep2(const float* __restrict__ h0, uint16_t* __restrict__ h_hist,
                      uint32_t* __restrict__ flags){
  int i = blockIdx.x*256 + threadIdx.x;   // grid 512 -> 131072 threads
  if (i < 65536){
    int rw = i >> 9, k = i & 511;         // row = (s*64+b), both segments start at h0[b]
    h_hist[i] = f2b(h0[(size_t)(rw & 63)*512 + k]);
  }
  if (i < 129*8*64) flags[i] = 0u;        // 66048 dwords
}

// ---------------- tembk: timestep embedding, bf16 ----------------
__global__ void tembk(const float* __restrict__ x, uint16_t* __restrict__ temb){
  const int rid = blockIdx.x;       // (b*128 + t)
  const int k = threadIdx.x;        // 0..255
  float x0 = x[(size_t)rid*16 + 0], x1 = x[(size_t)rid*16 + 1];
  float f = __expf((float)k * (-9.210340371976184f/256.f));  // 10000^(-k/256)
  float a0 = x0*f, a1 = x1*f;
  size_t base = (size_t)rid*1024;
  temb[base + k]        = f2b(__cosf(a0));
  temb[base + 256 + k]  = f2b(__sinf(a0));
  temb[base + 512 + k]  = f2b(__cosf(a1));
  temb[base + 768 + k]  = f2b(__sinf(a1));
}

// ---------------- gemmB: G = temb[8192,1024] @ wmid[2048,1024]^T  (bf16 MFMA) ----------------
__launch_bounds__(256)
__global__ void gemmB(const uint16_t* __restrict__ temb, const uint16_t* __restrict__ wmid,
                      uint16_t* __restrict__ G){
  __shared__ __align__(16) uint16_t Al[128][72];  // 64 + 8 pad
  __shared__ __align__(16) uint16_t Bl[128][72];
  const int tid = threadIdx.x;
  const int m0 = blockIdx.x*128, n0 = blockIdx.y*128;
  const int w = tid >> 6, lane = tid & 63;
  const int q = lane >> 4, ln = lane & 15;
  const int wm = w >> 1, wn = w & 1;
  const int srow = tid >> 1, shalf = tid & 1;

  f32x4_t acc[4][4];
  #pragma unroll
  for (int a = 0; a < 4; ++a)
    #pragma unroll
    for (int b = 0; b < 4; ++b) acc[a][b] = (f32x4_t){0.f,0.f,0.f,0.f};

  for (int kb = 0; kb < 16; ++kb){
    const uint4* ga = (const uint4*)(temb + (size_t)(m0 + srow)*1024 + kb*64 + shalf*32);
    const uint4* gb = (const uint4*)(wmid + (size_t)(n0 + srow)*1024 + kb*64 + shalf*32);
    uint4 va[4], vb[4];
    #pragma unroll
    for (int i = 0; i < 4; ++i){ va[i] = ga[i]; vb[i] = gb[i]; }
    #pragma unroll
    for (int i = 0; i < 4; ++i){
      *(uint4*)&Al[srow][shalf*32 + i*8] = va[i];
      *(uint4*)&Bl[srow][shalf*32 + i*8] = vb[i];
    }
    __syncthreads();
    #pragma unroll
    for (int kc = 0; kc < 2; ++kc){
      bf16x8_t af[4], bf[4];
      #pragma unroll
      for (int mt = 0; mt < 4; ++mt) af[mt] = *(const bf16x8_t*)&Al[wm*64 + mt*16 + ln][kc*32 + q*8];
      #pragma unroll
      for (int nt = 0; nt < 4; ++nt) bf[nt] = *(const bf16x8_t*)&Bl[wn*64 + nt*16 + ln][kc*32 + q*8];
      #pragma unroll
      for (int mt = 0; mt < 4; ++mt)
        #pragma unroll
        for (int nt = 0; nt < 4; ++nt)
          acc[mt][nt] = __builtin_amdgcn_mfma_f32_16x16x32_bf16(af[mt], bf[nt], acc[mt][nt], 0, 0, 0);
    }
    __syncthreads();
  }
  #pragma unroll
  for (int mt = 0; mt < 4; ++mt)
    #pragma unroll
    for (int nt = 0; nt < 4; ++nt)
      #pragma unroll
      for (int r = 0; r < 4; ++r){
        int Mr = m0 + wm*64 + mt*16 + q*4 + r;    // C/D: col=lane&15, row=quad*4+reg (m89-verified)
        int Nc = n0 + wn*64 + nt*16 + ln;
        G[(size_t)Mr*2048 + Nc] = f2b(acc[mt][nt][r]);
      }
}

// ---------------- lstmk: persistent recurrence (R4 restructure) ----------------
// 128 blocks = 8 row-groups (16 rows) x 16 col-groups (32 units). blockIdx = g*8 + rr.
__launch_bounds__(256)
__global__ void lstmk(const float* __restrict__ x, const float* __restrict__ c0,
                      const int* __restrict__ lengths,
                      const uint16_t* __restrict__ whh_b, const uint16_t* __restrict__ G,
                      const float* __restrict__ wc0, const float* __restrict__ wc1,
                      const float* __restrict__ bc,
                      uint16_t* __restrict__ h_hist, float* __restrict__ hfin,
                      uint32_t* __restrict__ flags){
  __shared__ __align__(16) uint16_t h_l[16][552];   // cols 0..511 h, 512..519 xf, 520..543 zeros, pad

  const int tid = threadIdx.x;
  const int bid = blockIdx.x;
  const int rr = bid & 7;         // row-group
  const int g  = bid >> 3;        // col-group
  const int k0 = g*32;
  const int sp = rr >> 2;         // segment of this row-group
  const int w = tid >> 6, lane = tid & 63;
  const int q = lane >> 4, ln = lane & 15;
  const int u8 = ln & 7, gh = ln >> 3;          // unit-in-octet, gate-half
  const int unit = k0 + w*8 + u8;               // this lane's hidden unit
  const int gl0 = gh*512 + unit;                // tile0 gate rows: i (gh=0), f (gh=1)
  const int gl1 = (2 + gh)*512 + unit;          // tile1 gate rows: g (gh=0), o (gh=1)

  // W_hh B-fragments resident in VGPRs, remapped N-tiles.
  bf16x8_t barr0[16], barr1[16];
  #pragma unroll
  for (int kc = 0; kc < 16; ++kc){
    barr0[kc] = *(const bf16x8_t*)(whh_b + (size_t)gl0*512 + kc*32 + q*8);
    barr1[kc] = *(const bf16x8_t*)(whh_b + (size_t)gl1*512 + kc*32 + q*8);
  }
  // K-extension B-fragments (xf @ Wc): rows k=512+q*8+j; only q==0 carries Wc, others zero.
  bf16x8_t e0f[2], e1f[2];
  #pragma unroll
  for (int nsI = 0; nsI < 2; ++nsI){
    bf16x8_t v0 = {0,0,0,0,0,0,0,0}, v1 = {0,0,0,0,0,0,0,0};
    if (q == 0){
      const float* wcs = nsI ? wc1 : wc0;
      #pragma unroll
      for (int j = 0; j < 8; ++j){
        ((uint16_t*)&v0)[j] = f2b(wcs[gl0*8 + j]);
        ((uint16_t*)&v1)[j] = f2b(wcs[gl1*8 + j]);
      }
    }
    e0f[nsI] = v0; e1f[nsI] = v1;
  }
  // biases per lane (per ns)
  float bc0v[2] = { bc[gl0], bc[2048 + gl0] };
  float bc1v[2] = { bc[gl1], bc[2048 + gl1] };

  // per-lane row ownership (C-layout rows q*4+r), cell state for ln<8 lanes
  int   bmr[4], lenr[4];
  float cst[4];
  #pragma unroll
  for (int r = 0; r < 4; ++r){
    int row = rr*16 + q*4 + r;
    bmr[r]  = row & 63;
    lenr[r] = lengths[bmr[r]];
    cst[r]  = c0[(size_t)bmr[r]*512 + unit];
  }

  // h staging map: thread -> (row hm, 32-col chunk sg)
  const int hm = tid >> 4, sg = tid & 15;
  // xf staging map (tid<128): (row xm, col xc)
  const int xm = tid >> 3, xc = tid & 7;
  const int xb = (rr*16 + xm) & 63;

  // zero the K-extension tail (cols 520..543) once
  for (int idx = tid; idx < 16*32; idx += 256){
    h_l[idx >> 5][520 + (idx & 31)] = 0;
  }
  __syncthreads();

  for (int t = 0; t < 128; ++t){
    const int qidx = sp*128 + t;
    const int ntm = qidx >> 1;     // source timestep (reshape interleave)
    const int ns  = qidx & 1;      // embedding branch

    // --- early independent loads: G slice (C-layout, cached) + xf source ---
    uint16_t g0r[4], g1r[4];
    #pragma unroll
    for (int r = 0; r < 4; ++r){
      size_t grow = (size_t)(bmr[r]*128 + ntm)*2048;
      g0r[r] = G[grow + gl0];
      g1r[r] = G[grow + gl1];
    }
    float xv = 0.f;
    if (tid < 128){
      if (ns == 0)      xv = x[(size_t)(xb*128 + ntm)*16 + 2 + xc];
      else if (xc < 6)  xv = x[(size_t)(xb*128 + ntm)*16 + 10 + xc];
    }

    // --- poll: one flag per lane (64 producer waves per row-group) ---
    if (t > 0){
      uint32_t* fl = (uint32_t*)(flags + ((size_t)t*8 + rr)*64);
      while (true){
        uint32_t v = __hip_atomic_load(&fl[lane], __ATOMIC_RELAXED, __HIP_MEMORY_SCOPE_AGENT);
        if (__all(v != 0u)) break;
        __builtin_amdgcn_s_sleep(1);
      }
      __builtin_amdgcn_fence(__ATOMIC_ACQUIRE, "workgroup");  // compiler barrier; no L2 inv
    }
    // stage h_t (32 bf16/thread, agent-scope LLC loads) + xf into K-extension cols
    {
      unsigned long long* hp = (unsigned long long*)
          (h_hist + ((size_t)t*128 + rr*16 + hm)*512 + sg*32);
      unsigned long long hv[8];
      #pragma unroll
      for (int i = 0; i < 8; ++i)
        hv[i] = __hip_atomic_load(&hp[i], __ATOMIC_RELAXED, __HIP_MEMORY_SCOPE_AGENT);
      #pragma unroll
      for (int i = 0; i < 8; ++i)
        *(unsigned long long*)&h_l[hm][sg*32 + i*4] = hv[i];
    }
    if (tid < 128) h_l[xm][512 + xc] = f2b(xv);
    __syncthreads();   // sync 1 (the only barrier per step)

    // --- gates = G + bias + [h|xf] @ [Whh|Wc]^T  (17 kc chunks) ---
    f32x4_t acc0, acc1;
    {
      float b0 = ns ? bc0v[1] : bc0v[0];
      float b1 = ns ? bc1v[1] : bc1v[0];
      #pragma unroll
      for (int r = 0; r < 4; ++r){ acc0[r] = bf2f(g0r[r]) + b0; acc1[r] = bf2f(g1r[r]) + b1; }
    }
    #pragma unroll
    for (int kc = 0; kc < 16; ++kc){
      bf16x8_t a = *(const bf16x8_t*)&h_l[ln][kc*32 + q*8];
      acc0 = __builtin_amdgcn_mfma_f32_16x16x32_bf16(a, barr0[kc], acc0, 0, 0, 0);
      acc1 = __builtin_amdgcn_mfma_f32_16x16x32_bf16(a, barr1[kc], acc1, 0, 0, 0);
    }
    {
      bf16x8_t a = *(const bf16x8_t*)&h_l[ln][512 + q*8];
      acc0 = __builtin_amdgcn_mfma_f32_16x16x32_bf16(a, ns ? e0f[1] : e0f[0], acc0, 0, 0, 0);
      acc1 = __builtin_amdgcn_mfma_f32_16x16x32_bf16(a, ns ? e1f[1] : e1f[0], acc1, 0, 0, 0);
    }

    // --- register gate exchange: lane ln has (i,g) for gh=0, (f,o) for gh=1 ---
    float pf[4], po[4];
    #pragma unroll
    for (int r = 0; r < 4; ++r){
      pf[r] = __shfl_xor(acc0[r], 8);
      po[r] = __shfl_xor(acc1[r], 8);
    }
    if (ln < 8){
      uint32_t hb[4]; float hF[4];
      #pragma unroll
      for (int r = 0; r < 4; ++r){
        float ig = acc0[r], fg = pf[r], gg = acc1[r], og = po[r];
        cst[r] = sigm(fg)*cst[r] + sigm(ig)*tanh_(gg);
        float h = sigm(og)*tanh_(cst[r]);
        hF[r] = h; hb[r] = (uint32_t)f2b(h);
      }
      #pragma unroll
      for (int r = 0; r < 4; ++r){
        uint32_t ph = (uint32_t)__shfl_xor((int)hb[r], 1);
        if (!(ln & 1)){
          uint32_t packed = hb[r] | (ph << 16);
          uint32_t* hp = (uint32_t*)(h_hist + ((size_t)(t+1)*128 + rr*16 + q*4 + r)*512 + unit);
          __hip_atomic_store(hp, packed, __ATOMIC_RELAXED, __HIP_MEMORY_SCOPE_AGENT);
        }
        if (t == lenr[r] - 1)
          hfin[(size_t)bmr[r]*1024 + sp*512 + unit] = hF[r];
      }
    }
    // per-wave flag: RELEASE drains this wave's h stores (vmcnt 0) before flag lands in LLC
    if (lane == 0)
      __hip_atomic_store((uint32_t*)&flags[((size_t)(t+1)*8 + rr)*64 + g*4 + w], 1u,
                         __ATOMIC_RELEASE, __HIP_MEMORY_SCOPE_AGENT);
  }
}

// ---------------- outk: out = sigmoid(hfin @ W_o^T + b_o) ----------------
__global__ void outk(const float* __restrict__ hfin, const float* __restrict__ W_o,
                     const float* __restrict__ b_o, float* __restrict__ out){
  __shared__ float hl[1024];
  __shared__ float red[16][17];
  const int b = blockIdx.x, tid = threadIdx.x;
  #pragma unroll
  for (int i = 0; i < 4; ++i) hl[tid + i*256] = hfin[(size_t)b*1024 + tid + i*256];
  __syncthreads();
  const int o = tid >> 4, j0 = tid & 15;
  float s = 0.f;
  if (o < 14){
    for (int j = j0; j < 1024; j += 16) s += hl[j]*W_o[(size_t)o*1024 + j];
  }
  red[o][j0] = s;
  __syncthreads();
  if (tid < 14){
    float tot = b_o[tid];
    #pragma unroll
    for (int i = 0; i < 16; ++i) tot += red[tid][i];
    out[b*14 + tid] = 1.0f/(1.0f + __expf(-tot));
  }
}

extern "C" void kernel_launch(void* const* d_in, const int* in_sizes, int n_in,
                              void* d_out, int out_size, void* d_ws, size_t ws_size,
                              hipStream_t stream){
  const float* x     = (const float*)d_in[0];
  const int*   lens  = (const int*)  d_in[1];
  const float* h0    = (const float*)d_in[2];
  const float* c0    = (const float*)d_in[3];
  const float* W_is0 = (const float*)d_in[4];
  const float* b_is0 = (const float*)d_in[5];
  const float* W_is1 = (const float*)d_in[6];
  const float* b_is1 = (const float*)d_in[7];
  const float* W_ih  = (const float*)d_in[8];
  const float* W_hh  = (const float*)d_in[9];
  const float* b_ih  = (const float*)d_in[10];
  const float* b_hh  = (const float*)d_in[11];
  const float* W_o   = (const float*)d_in[12];
  const float* b_o   = (const float*)d_in[13];
  float* out = (float*)d_out;

  char* ws = (char*)d_ws;   // needs ~74.2 MB
  uint16_t* G      = (uint16_t*)(ws + OFF_G);
  uint16_t* temb   = (uint16_t*)(ws + OFF_TEMB);
  uint16_t* h_hist = (uint16_t*)(ws + OFF_HH);
  uint16_t* whh_b  = (uint16_t*)(ws + OFF_WHH);
  uint16_t* wmid_b = (uint16_t*)(ws + OFF_WMID);
  float* wc0  = (float*)(ws + OFF_WC0);
  float* wc1  = (float*)(ws + OFF_WC1);
  float* bc   = (float*)(ws + OFF_BC);
  float* hfin = (float*)(ws + OFF_HFIN);
  uint32_t* flags = (uint32_t*)(ws + OFF_FLAGS);

  hipLaunchKernelGGL(prep1, dim3(2048), dim3(256), 0, stream,
                     W_ih, W_hh, W_is0, b_is0, W_is1, b_is1, b_ih, b_hh,
                     whh_b, wmid_b, wc0, wc1, bc);
  hipLaunchKernelGGL(prep2, dim3(512), dim3(256), 0, stream, h0, h_hist, flags);
  hipLaunchKernelGGL(tembk, dim3(8192), dim3(256), 0, stream, x, temb);
  hipLaunchKernelGGL(gemmB, dim3(64, 16), dim3(256), 0, stream, temb, wmid_b, G);
  hipLaunchKernelGGL(lstmk, dim3(128), dim3(256), 0, stream,
                     x, c0, lens, whh_b, G, wc0, wc1, bc, h_hist, hfin, flags);
  hipLaunchKernelGGL(outk, dim3(64), dim3(256), 0, stream, hfin, W_o, b_o, out);
}

// Round 5
// 656.209 us; speedup vs baseline: 2.5020x; 2.5020x over previous
//
#include <hip/hip_runtime.h>
#include <hip/hip_bf16.h>
#include <stdint.h>

// Problem: B=64, T=128, F=16, H=512, S=2.  All inputs fp32, lengths int32, out fp32 [64][14].
//
// R1: fixed half-staged h_l (NaN). R2: 1338us. R3: relaxed poll (no per-iter L2 inv) -> 831us
// (lstmk 635us). R4: slim compute but per-wave RELEASE flags (4x cache-maintenance/block-step)
// + 64-wide join -> regressed to 1450us.
// R5: eliminate the flag protocol entirely -- POLL ON THE DATA:
//   - prep2 fills h_hist[1..128] with sentinel 0xAAAAAAAA; producers fire-and-forget relaxed
//     agent stores (NO vmcnt drain, NO release, NO wbl2/inv anywhere in the loop).
//   - consumers poll their h-words (8x u64 agent loads) until every u32 != sentinel; on exit
//     the registers already hold h -> per-step protocol cost = one-way visibility + detect,
//     instead of R3's ~4 serial LLC round-trips (drain, flag store, flag poll, h load).
//   - h values that would collide with the sentinel get bit0 flipped (1 ulp at 3e-13; h0>=0
//     can't collide but gets the same guard).
//   - h_l double-buffered by t&1 (replaces the WAR protection the flag join provided);
//     still exactly one __syncthreads per step.
//   - keeps R4's slim compute: shfl_xor cell update (no gates LDS), G+bias direct into MFMA
//     accumulator (C-layout), xf@Wc folded into MFMA K-extension (K=512->544).
//
// Reshape quirk (faithful to torch): segment s', step t' uses source timestep n_t=(s'*128+t')>>1
// and embedding branch n_s=(s'*128+t')&1.

typedef __attribute__((ext_vector_type(8))) short bf16x8_t;
typedef __attribute__((ext_vector_type(4))) float f32x4_t;

#define SENT 0xAAAAAAAAu

// ---------------- workspace layout (bytes) ----------------
#define OFF_G      0u                      // bf16 [8192][2048]   33,554,432
#define OFF_TEMB   33554432u               // bf16 [8192][1024]   16,777,216
#define OFF_HH     50331648u               // bf16 [129][128][512] 16,908,288
#define OFF_WHH    67239936u               // bf16 [2048][512]     2,097,152
#define OFF_WMID   69337088u               // bf16 [2048][1024]    4,194,304
#define OFF_WC0    73531392u               // f32  [2048][8]          65,536
#define OFF_WC1    73596928u               // f32  [2048][8] (6 used) 65,536
#define OFF_BC     73662464u               // f32  [2][2048]          16,384
#define OFF_HFIN   73678848u               // f32  [64][1024]        262,144
// total ~74 MB

__device__ __forceinline__ float bf2f(uint16_t u){
  union { uint32_t i; float f; } v; v.i = ((uint32_t)u) << 16; return v.f;
}
__device__ __forceinline__ uint16_t f2b(float f){
  union { float f; uint32_t i; } v; v.f = f;
  uint32_t r = v.i + 0x7fffu + ((v.i >> 16) & 1u);  // RNE
  return (uint16_t)(r >> 16);
}
__device__ __forceinline__ float sigm(float x){ return 1.0f/(1.0f + __expf(-x)); }
__device__ __forceinline__ float tanh_(float x){
  float xc = fminf(fmaxf(x, -15.f), 15.f);
  float t = __expf(2.f*xc);
  return (t - 1.f)/(t + 1.f);
}

// ---------------- prep1: weight folding + bf16 casts ----------------
__global__ void prep1(const float* __restrict__ W_ih, const float* __restrict__ W_hh,
                      const float* __restrict__ W_is0, const float* __restrict__ b_is0,
                      const float* __restrict__ W_is1, const float* __restrict__ b_is1,
                      const float* __restrict__ b_ih, const float* __restrict__ b_hh,
                      uint16_t* __restrict__ whh_b, uint16_t* __restrict__ wmid_b,
                      float* __restrict__ wc0, float* __restrict__ wc1, float* __restrict__ bc){
  const int n = blockIdx.x;        // gate column 0..2047
  const int tid = threadIdx.x;     // 256
  __shared__ float wrow[512];
  wrow[tid]       = W_ih[(size_t)n*1536 + tid];
  wrow[tid + 256] = W_ih[(size_t)n*1536 + 256 + tid];
  for (int j = tid; j < 1024; j += 256)
    wmid_b[(size_t)n*1024 + j] = f2b(W_ih[(size_t)n*1536 + 512 + j]);
  for (int k = tid; k < 512; k += 256)
    whh_b[(size_t)n*512 + k] = f2b(W_hh[(size_t)n*512 + k]);
  __syncthreads();
  if (tid < 8){
    float s = 0.f;
    for (int k = 0; k < 512; ++k) s += wrow[k]*W_is0[k*8 + tid];
    wc0[n*8 + tid] = s;
  } else if (tid < 16){
    int c = tid - 8;
    float s = 0.f;
    if (c < 6){ for (int k = 0; k < 512; ++k) s += wrow[k]*W_is1[k*6 + c]; }
    wc1[n*8 + c] = s;              // c==6,7 stay 0 (stride-8 padding)
  } else if (tid == 16){
    float s = b_ih[n] + b_hh[n];
    for (int k = 0; k < 512; ++k) s += wrow[k]*b_is0[k];
    bc[n] = s;
  } else if (tid == 17){
    float s = b_ih[n] + b_hh[n];
    for (int k = 0; k < 512; ++k) s += wrow[k]*b_is1[k];
    bc[2048 + n] = s;
  }
}

// ---------------- prep2: h_hist[0]=h0, h_hist[1..128]=sentinel ----------------
__global__ void prep2(const float* __restrict__ h0, uint16_t* __restrict__ h_hist){
  int i = blockIdx.x*256 + threadIdx.x;   // grid 16512 -> 4,227,072 u32 words
  uint32_t* hh = (uint32_t*)h_hist;
  if (i < 32768){                          // level 0: 128 rows x 512 bf16 = 32768 u32
    int rw = i >> 8, k = (i & 255)*2;      // row = (s*64+b); both segments start at h0[b]
    uint32_t lo = f2b(h0[(size_t)(rw & 63)*512 + k]);
    uint32_t hi = f2b(h0[(size_t)(rw & 63)*512 + k + 1]);
    uint32_t w = lo | (hi << 16);
    if (w == SENT) w ^= 1u;                // can't happen (h0>=0) but cheap guard
    hh[i] = w;
  } else if (i < 4227072){
    hh[i] = SENT;
  }
}

// ---------------- tembk: timestep embedding, bf16 ----------------
__global__ void tembk(const float* __restrict__ x, uint16_t* __restrict__ temb){
  const int rid = blockIdx.x;       // (b*128 + t)
  const int k = threadIdx.x;        // 0..255
  float x0 = x[(size_t)rid*16 + 0], x1 = x[(size_t)rid*16 + 1];
  float f = __expf((float)k * (-9.210340371976184f/256.f));  // 10000^(-k/256)
  float a0 = x0*f, a1 = x1*f;
  size_t base = (size_t)rid*1024;
  temb[base + k]        = f2b(__cosf(a0));
  temb[base + 256 + k]  = f2b(__sinf(a0));
  temb[base + 512 + k]  = f2b(__cosf(a1));
  temb[base + 768 + k]  = f2b(__sinf(a1));
}

// ---------------- gemmB: G = temb[8192,1024] @ wmid[2048,1024]^T  (bf16 MFMA) ----------------
__launch_bounds__(256)
__global__ void gemmB(const uint16_t* __restrict__ temb, const uint16_t* __restrict__ wmid,
                      uint16_t* __restrict__ G){
  __shared__ __align__(16) uint16_t Al[128][72];  // 64 + 8 pad
  __shared__ __align__(16) uint16_t Bl[128][72];
  const int tid = threadIdx.x;
  const int m0 = blockIdx.x*128, n0 = blockIdx.y*128;
  const int w = tid >> 6, lane = tid & 63;
  const int q = lane >> 4, ln = lane & 15;
  const int wm = w >> 1, wn = w & 1;
  const int srow = tid >> 1, shalf = tid & 1;

  f32x4_t acc[4][4];
  #pragma unroll
  for (int a = 0; a < 4; ++a)
    #pragma unroll
    for (int b = 0; b < 4; ++b) acc[a][b] = (f32x4_t){0.f,0.f,0.f,0.f};

  for (int kb = 0; kb < 16; ++kb){
    const uint4* ga = (const uint4*)(temb + (size_t)(m0 + srow)*1024 + kb*64 + shalf*32);
    const uint4* gb = (const uint4*)(wmid + (size_t)(n0 + srow)*1024 + kb*64 + shalf*32);
    uint4 va[4], vb[4];
    #pragma unroll
    for (int i = 0; i < 4; ++i){ va[i] = ga[i]; vb[i] = gb[i]; }
    #pragma unroll
    for (int i = 0; i < 4; ++i){
      *(uint4*)&Al[srow][shalf*32 + i*8] = va[i];
      *(uint4*)&Bl[srow][shalf*32 + i*8] = vb[i];
    }
    __syncthreads();
    #pragma unroll
    for (int kc = 0; kc < 2; ++kc){
      bf16x8_t af[4], bf[4];
      #pragma unroll
      for (int mt = 0; mt < 4; ++mt) af[mt] = *(const bf16x8_t*)&Al[wm*64 + mt*16 + ln][kc*32 + q*8];
      #pragma unroll
      for (int nt = 0; nt < 4; ++nt) bf[nt] = *(const bf16x8_t*)&Bl[wn*64 + nt*16 + ln][kc*32 + q*8];
      #pragma unroll
      for (int mt = 0; mt < 4; ++mt)
        #pragma unroll
        for (int nt = 0; nt < 4; ++nt)
          acc[mt][nt] = __builtin_amdgcn_mfma_f32_16x16x32_bf16(af[mt], bf[nt], acc[mt][nt], 0, 0, 0);
    }
    __syncthreads();
  }
  #pragma unroll
  for (int mt = 0; mt < 4; ++mt)
    #pragma unroll
    for (int nt = 0; nt < 4; ++nt)
      #pragma unroll
      for (int r = 0; r < 4; ++r){
        int Mr = m0 + wm*64 + mt*16 + q*4 + r;    // C/D: col=lane&15, row=quad*4+reg (m89-verified)
        int Nc = n0 + wn*64 + nt*16 + ln;
        G[(size_t)Mr*2048 + Nc] = f2b(acc[mt][nt][r]);
      }
}

// ---------------- lstmk: persistent recurrence (R5: poll-on-data) ----------------
// 128 blocks = 8 row-groups (16 rows) x 16 col-groups (32 units). blockIdx = g*8 + rr.
__launch_bounds__(256)
__global__ void lstmk(const float* __restrict__ x, const float* __restrict__ c0,
                      const int* __restrict__ lengths,
                      const uint16_t* __restrict__ whh_b, const uint16_t* __restrict__ G,
                      const float* __restrict__ wc0, const float* __restrict__ wc1,
                      const float* __restrict__ bc,
                      uint16_t* __restrict__ h_hist, float* __restrict__ hfin){
  __shared__ __align__(16) uint16_t h_l[2][16][552]; // cols 0..511 h, 512..519 xf, 520..543 zeros

  const int tid = threadIdx.x;
  const int bid = blockIdx.x;
  const int rr = bid & 7;         // row-group
  const int g  = bid >> 3;        // col-group
  const int k0 = g*32;
  const int sp = rr >> 2;         // segment of this row-group
  const int w = tid >> 6, lane = tid & 63;
  const int q = lane >> 4, ln = lane & 15;
  const int u8 = ln & 7, gh = ln >> 3;          // unit-in-octet, gate-half
  const int unit = k0 + w*8 + u8;               // this lane's hidden unit
  const int gl0 = gh*512 + unit;                // tile0 gate rows: i (gh=0), f (gh=1)
  const int gl1 = (2 + gh)*512 + unit;          // tile1 gate rows: g (gh=0), o (gh=1)

  // W_hh B-fragments resident in VGPRs/AGPRs, remapped N-tiles.
  bf16x8_t barr0[16], barr1[16];
  #pragma unroll
  for (int kc = 0; kc < 16; ++kc){
    barr0[kc] = *(const bf16x8_t*)(whh_b + (size_t)gl0*512 + kc*32 + q*8);
    barr1[kc] = *(const bf16x8_t*)(whh_b + (size_t)gl1*512 + kc*32 + q*8);
  }
  // K-extension B-fragments (xf @ Wc): rows k=512+q*8+j; only q==0 carries Wc, others zero.
  bf16x8_t e0f[2], e1f[2];
  #pragma unroll
  for (int nsI = 0; nsI < 2; ++nsI){
    bf16x8_t v0 = {0,0,0,0,0,0,0,0}, v1 = {0,0,0,0,0,0,0,0};
    if (q == 0){
      const float* wcs = nsI ? wc1 : wc0;
      #pragma unroll
      for (int j = 0; j < 8; ++j){
        ((uint16_t*)&v0)[j] = f2b(wcs[gl0*8 + j]);
        ((uint16_t*)&v1)[j] = f2b(wcs[gl1*8 + j]);
      }
    }
    e0f[nsI] = v0; e1f[nsI] = v1;
  }
  // biases per lane (per ns)
  float bc0v[2] = { bc[gl0], bc[2048 + gl0] };
  float bc1v[2] = { bc[gl1], bc[2048 + gl1] };

  // per-lane row ownership (C-layout rows q*4+r), cell state for ln<8 lanes
  int   bmr[4], lenr[4];
  float cst[4];
  #pragma unroll
  for (int r = 0; r < 4; ++r){
    int row = rr*16 + q*4 + r;
    bmr[r]  = row & 63;
    lenr[r] = lengths[bmr[r]];
    cst[r]  = c0[(size_t)bmr[r]*512 + unit];
  }

  // h staging map: thread -> (row hm, 32-col chunk sg)
  const int hm = tid >> 4, sg = tid & 15;
  // xf staging map (tid<128): (row xm, col xc)
  const int xm = tid >> 3, xc = tid & 7;
  const int xb = (rr*16 + xm) & 63;

  // zero the K-extension tail (cols 520..543), both buffers (NaN-in-stale-LDS guard)
  for (int idx = tid; idx < 2*16*32; idx += 256)
    h_l[idx >> 9][(idx >> 5) & 15][520 + (idx & 31)] = 0;

  for (int t = 0; t < 128; ++t){
    const int qidx = sp*128 + t;
    const int ntm = qidx >> 1;     // source timestep (reshape interleave)
    const int ns  = qidx & 1;      // embedding branch

    // --- early independent loads: G slice (C-layout, cached) + xf source ---
    uint16_t g0r[4], g1r[4];
    #pragma unroll
    for (int r = 0; r < 4; ++r){
      size_t grow = (size_t)(bmr[r]*128 + ntm)*2048;
      g0r[r] = G[grow + gl0];
      g1r[r] = G[grow + gl1];
    }
    float xv = 0.f;
    if (tid < 128){
      if (ns == 0)      xv = x[(size_t)(xb*128 + ntm)*16 + 2 + xc];
      else if (xc < 6)  xv = x[(size_t)(xb*128 + ntm)*16 + 10 + xc];
    }

    // --- poll-on-data: re-load own 32 bf16 until no u32 equals the sentinel ---
    {
      unsigned long long* hp = (unsigned long long*)
          (h_hist + ((size_t)t*128 + rr*16 + hm)*512 + sg*32);
      unsigned long long hv[8];
      while (true){
        bool ok = true;
        #pragma unroll
        for (int i = 0; i < 8; ++i){
          hv[i] = __hip_atomic_load(&hp[i], __ATOMIC_RELAXED, __HIP_MEMORY_SCOPE_AGENT);
          ok &= ((uint32_t)hv[i] != SENT) & ((uint32_t)(hv[i] >> 32) != SENT);
        }
        if (ok) break;
        __builtin_amdgcn_s_sleep(1);
      }
      #pragma unroll
      for (int i = 0; i < 8; ++i)
        *(unsigned long long*)&h_l[t & 1][hm][sg*32 + i*4] = hv[i];
    }
    if (tid < 128) h_l[t & 1][xm][512 + xc] = f2b(xv);
    __syncthreads();   // the only barrier per step (stage -> MFMA read)

    // --- gates = G + bias + [h|xf] @ [Whh|Wc]^T  (17 kc chunks) ---
    f32x4_t acc0, acc1;
    {
      float b0 = ns ? bc0v[1] : bc0v[0];
      float b1 = ns ? bc1v[1] : bc1v[0];
      #pragma unroll
      for (int r = 0; r < 4; ++r){ acc0[r] = bf2f(g0r[r]) + b0; acc1[r] = bf2f(g1r[r]) + b1; }
    }
    #pragma unroll
    for (int kc = 0; kc < 16; ++kc){
      bf16x8_t a = *(const bf16x8_t*)&h_l[t & 1][ln][kc*32 + q*8];
      acc0 = __builtin_amdgcn_mfma_f32_16x16x32_bf16(a, barr0[kc], acc0, 0, 0, 0);
      acc1 = __builtin_amdgcn_mfma_f32_16x16x32_bf16(a, barr1[kc], acc1, 0, 0, 0);
    }
    {
      bf16x8_t a = *(const bf16x8_t*)&h_l[t & 1][ln][512 + q*8];
      acc0 = __builtin_amdgcn_mfma_f32_16x16x32_bf16(a, ns ? e0f[1] : e0f[0], acc0, 0, 0, 0);
      acc1 = __builtin_amdgcn_mfma_f32_16x16x32_bf16(a, ns ? e1f[1] : e1f[0], acc1, 0, 0, 0);
    }

    // --- register gate exchange: lane ln has (i,g) for gh=0, (f,o) for gh=1 ---
    float pf[4], po[4];
    #pragma unroll
    for (int r = 0; r < 4; ++r){
      pf[r] = __shfl_xor(acc0[r], 8);
      po[r] = __shfl_xor(acc1[r], 8);
    }
    if (ln < 8){
      uint32_t hb[4]; float hF[4];
      #pragma unroll
      for (int r = 0; r < 4; ++r){
        float ig = acc0[r], fg = pf[r], gg = acc1[r], og = po[r];
        cst[r] = sigm(fg)*cst[r] + sigm(ig)*tanh_(gg);
        float h = sigm(og)*tanh_(cst[r]);
        hF[r] = h; hb[r] = (uint32_t)f2b(h);
      }
      #pragma unroll
      for (int r = 0; r < 4; ++r){
        uint32_t ph = (uint32_t)__shfl_xor((int)hb[r], 1);
        if (!(ln & 1)){
          uint32_t packed = hb[r] | (ph << 16);
          if (packed == SENT) packed ^= 1u;   // 1-ulp-at-3e-13 guard vs sentinel collision
          uint32_t* hp = (uint32_t*)(h_hist + ((size_t)(t+1)*128 + rr*16 + q*4 + r)*512 + unit);
          __hip_atomic_store(hp, packed, __ATOMIC_RELAXED, __HIP_MEMORY_SCOPE_AGENT);
        }
        if (t == lenr[r] - 1)
          hfin[(size_t)bmr[r]*1024 + sp*512 + unit] = hF[r];
      }
    }
    // no flag, no drain: the data is the flag.
  }
}

// ---------------- outk: out = sigmoid(hfin @ W_o^T + b_o) ----------------
__global__ void outk(const float* __restrict__ hfin, const float* __restrict__ W_o,
                     const float* __restrict__ b_o, float* __restrict__ out){
  __shared__ float hl[1024];
  __shared__ float red[16][17];
  const int b = blockIdx.x, tid = threadIdx.x;
  #pragma unroll
  for (int i = 0; i < 4; ++i) hl[tid + i*256] = hfin[(size_t)b*1024 + tid + i*256];
  __syncthreads();
  const int o = tid >> 4, j0 = tid & 15;
  float s = 0.f;
  if (o < 14){
    for (int j = j0; j < 1024; j += 16) s += hl[j]*W_o[(size_t)o*1024 + j];
  }
  red[o][j0] = s;
  __syncthreads();
  if (tid < 14){
    float tot = b_o[tid];
    #pragma unroll
    for (int i = 0; i < 16; ++i) tot += red[tid][i];
    out[b*14 + tid] = 1.0f/(1.0f + __expf(-tot));
  }
}

extern "C" void kernel_launch(void* const* d_in, const int* in_sizes, int n_in,
                              void* d_out, int out_size, void* d_ws, size_t ws_size,
                              hipStream_t stream){
  const float* x     = (const float*)d_in[0];
  const int*   lens  = (const int*)  d_in[1];
  const float* h0    = (const float*)d_in[2];
  const float* c0    = (const float*)d_in[3];
  const float* W_is0 = (const float*)d_in[4];
  const float* b_is0 = (const float*)d_in[5];
  const float* W_is1 = (const float*)d_in[6];
  const float* b_is1 = (const float*)d_in[7];
  const float* W_ih  = (const float*)d_in[8];
  const float* W_hh  = (const float*)d_in[9];
  const float* b_ih  = (const float*)d_in[10];
  const float* b_hh  = (const float*)d_in[11];
  const float* W_o   = (const float*)d_in[12];
  const float* b_o   = (const float*)d_in[13];
  float* out = (float*)d_out;

  char* ws = (char*)d_ws;   // needs ~74 MB
  uint16_t* G      = (uint16_t*)(ws + OFF_G);
  uint16_t* temb   = (uint16_t*)(ws + OFF_TEMB);
  uint16_t* h_hist = (uint16_t*)(ws + OFF_HH);
  uint16_t* whh_b  = (uint16_t*)(ws + OFF_WHH);
  uint16_t* wmid_b = (uint16_t*)(ws + OFF_WMID);
  float* wc0  = (float*)(ws + OFF_WC0);
  float* wc1  = (float*)(ws + OFF_WC1);
  float* bc   = (float*)(ws + OFF_BC);
  float* hfin = (float*)(ws + OFF_HFIN);

  hipLaunchKernelGGL(prep1, dim3(2048), dim3(256), 0, stream,
                     W_ih, W_hh, W_is0, b_is0, W_is1, b_is1, b_ih, b_hh,
                     whh_b, wmid_b, wc0, wc1, bc);
  hipLaunchKernelGGL(prep2, dim3(16512), dim3(256), 0, stream, h0, h_hist);
  hipLaunchKernelGGL(tembk, dim3(8192), dim3(256), 0, stream, x, temb);
  hipLaunchKernelGGL(gemmB, dim3(64, 16), dim3(256), 0, stream, temb, wmid_b, G);
  hipLaunchKernelGGL(lstmk, dim3(128), dim3(256), 0, stream,
                     x, c0, lens, whh_b, G, wc0, wc1, bc, h_hist, hfin);
  hipLaunchKernelGGL(outk, dim3(64), dim3(256), 0, stream, hfin, W_o, b_o, out);
}

// Round 6
// 611.674 us; speedup vs baseline: 2.6841x; 1.0728x over previous
//
#include <hip/hip_runtime.h>
#include <hip/hip_bf16.h>
#include <stdint.h>

// Problem: B=64, T=128, F=16, H=512, S=2.  All inputs fp32, lengths int32, out fp32 [64][14].
//
// R1: fixed half-staged h_l (NaN). R2: 1338us. R3: relaxed poll -> 831us (lstmk 635).
// R4: per-wave RELEASE flags (cache-maintenance storm) -> regressed 1450us.
// R5: poll-on-data sentinel protocol (no flags, no drains, fire-and-forget stores) -> 656us
//     (lstmk 465us, 3.63us/step) — still latency-bound: the poll sweep was 8B x 64B-strided
//     agent loads = 262k uncoalesceable LLC transactions per iteration chip-wide.
// R6: COALESCED poll/stage mapping: thread j owns u64 words {j + 16*i} of its row (stride
//     128B) instead of a contiguous 64B chunk. Per poll instruction, lanes 0..15 now cover
//     128 contiguous bytes -> TA coalesces to line requests (~8 lines/wave/instr), ~8x less
//     LLC pressure per sweep. Everything else identical to R5.
//
// Reshape quirk (faithful to torch): segment s', step t' uses source timestep n_t=(s'*128+t')>>1
// and embedding branch n_s=(s'*128+t')&1.

typedef __attribute__((ext_vector_type(8))) short bf16x8_t;
typedef __attribute__((ext_vector_type(4))) float f32x4_t;

#define SENT 0xAAAAAAAAu

// ---------------- workspace layout (bytes) ----------------
#define OFF_G      0u                      // bf16 [8192][2048]   33,554,432
#define OFF_TEMB   33554432u               // bf16 [8192][1024]   16,777,216
#define OFF_HH     50331648u               // bf16 [129][128][512] 16,908,288
#define OFF_WHH    67239936u               // bf16 [2048][512]     2,097,152
#define OFF_WMID   69337088u               // bf16 [2048][1024]    4,194,304
#define OFF_WC0    73531392u               // f32  [2048][8]          65,536
#define OFF_WC1    73596928u               // f32  [2048][8] (6 used) 65,536
#define OFF_BC     73662464u               // f32  [2][2048]          16,384
#define OFF_HFIN   73678848u               // f32  [64][1024]        262,144
// total ~74 MB

__device__ __forceinline__ float bf2f(uint16_t u){
  union { uint32_t i; float f; } v; v.i = ((uint32_t)u) << 16; return v.f;
}
__device__ __forceinline__ uint16_t f2b(float f){
  union { float f; uint32_t i; } v; v.f = f;
  uint32_t r = v.i + 0x7fffu + ((v.i >> 16) & 1u);  // RNE
  return (uint16_t)(r >> 16);
}
__device__ __forceinline__ float sigm(float x){ return 1.0f/(1.0f + __expf(-x)); }
__device__ __forceinline__ float tanh_(float x){
  float xc = fminf(fmaxf(x, -15.f), 15.f);
  float t = __expf(2.f*xc);
  return (t - 1.f)/(t + 1.f);
}

// ---------------- prep1: weight folding + bf16 casts ----------------
__global__ void prep1(const float* __restrict__ W_ih, const float* __restrict__ W_hh,
                      const float* __restrict__ W_is0, const float* __restrict__ b_is0,
                      const float* __restrict__ W_is1, const float* __restrict__ b_is1,
                      const float* __restrict__ b_ih, const float* __restrict__ b_hh,
                      uint16_t* __restrict__ whh_b, uint16_t* __restrict__ wmid_b,
                      float* __restrict__ wc0, float* __restrict__ wc1, float* __restrict__ bc){
  const int n = blockIdx.x;        // gate column 0..2047
  const int tid = threadIdx.x;     // 256
  __shared__ float wrow[512];
  wrow[tid]       = W_ih[(size_t)n*1536 + tid];
  wrow[tid + 256] = W_ih[(size_t)n*1536 + 256 + tid];
  for (int j = tid; j < 1024; j += 256)
    wmid_b[(size_t)n*1024 + j] = f2b(W_ih[(size_t)n*1536 + 512 + j]);
  for (int k = tid; k < 512; k += 256)
    whh_b[(size_t)n*512 + k] = f2b(W_hh[(size_t)n*512 + k]);
  __syncthreads();
  if (tid < 8){
    float s = 0.f;
    for (int k = 0; k < 512; ++k) s += wrow[k]*W_is0[k*8 + tid];
    wc0[n*8 + tid] = s;
  } else if (tid < 16){
    int c = tid - 8;
    float s = 0.f;
    if (c < 6){ for (int k = 0; k < 512; ++k) s += wrow[k]*W_is1[k*6 + c]; }
    wc1[n*8 + c] = s;              // c==6,7 stay 0 (stride-8 padding)
  } else if (tid == 16){
    float s = b_ih[n] + b_hh[n];
    for (int k = 0; k < 512; ++k) s += wrow[k]*b_is0[k];
    bc[n] = s;
  } else if (tid == 17){
    float s = b_ih[n] + b_hh[n];
    for (int k = 0; k < 512; ++k) s += wrow[k]*b_is1[k];
    bc[2048 + n] = s;
  }
}

// ---------------- prep2: h_hist[0]=h0, h_hist[1..128]=sentinel ----------------
__global__ void prep2(const float* __restrict__ h0, uint16_t* __restrict__ h_hist){
  int i = blockIdx.x*256 + threadIdx.x;   // grid 16512 -> 4,227,072 u32 words
  uint32_t* hh = (uint32_t*)h_hist;
  if (i < 32768){                          // level 0: 128 rows x 512 bf16 = 32768 u32
    int rw = i >> 8, k = (i & 255)*2;      // row = (s*64+b); both segments start at h0[b]
    uint32_t lo = f2b(h0[(size_t)(rw & 63)*512 + k]);
    uint32_t hi = f2b(h0[(size_t)(rw & 63)*512 + k + 1]);
    uint32_t w = lo | (hi << 16);
    if (w == SENT) w ^= 1u;                // can't happen (h0>=0) but cheap guard
    hh[i] = w;
  } else if (i < 4227072){
    hh[i] = SENT;
  }
}

// ---------------- tembk: timestep embedding, bf16 ----------------
__global__ void tembk(const float* __restrict__ x, uint16_t* __restrict__ temb){
  const int rid = blockIdx.x;       // (b*128 + t)
  const int k = threadIdx.x;        // 0..255
  float x0 = x[(size_t)rid*16 + 0], x1 = x[(size_t)rid*16 + 1];
  float f = __expf((float)k * (-9.210340371976184f/256.f));  // 10000^(-k/256)
  float a0 = x0*f, a1 = x1*f;
  size_t base = (size_t)rid*1024;
  temb[base + k]        = f2b(__cosf(a0));
  temb[base + 256 + k]  = f2b(__sinf(a0));
  temb[base + 512 + k]  = f2b(__cosf(a1));
  temb[base + 768 + k]  = f2b(__sinf(a1));
}

// ---------------- gemmB: G = temb[8192,1024] @ wmid[2048,1024]^T  (bf16 MFMA) ----------------
__launch_bounds__(256)
__global__ void gemmB(const uint16_t* __restrict__ temb, const uint16_t* __restrict__ wmid,
                      uint16_t* __restrict__ G){
  __shared__ __align__(16) uint16_t Al[128][72];  // 64 + 8 pad
  __shared__ __align__(16) uint16_t Bl[128][72];
  const int tid = threadIdx.x;
  const int m0 = blockIdx.x*128, n0 = blockIdx.y*128;
  const int w = tid >> 6, lane = tid & 63;
  const int q = lane >> 4, ln = lane & 15;
  const int wm = w >> 1, wn = w & 1;
  const int srow = tid >> 1, shalf = tid & 1;

  f32x4_t acc[4][4];
  #pragma unroll
  for (int a = 0; a < 4; ++a)
    #pragma unroll
    for (int b = 0; b < 4; ++b) acc[a][b] = (f32x4_t){0.f,0.f,0.f,0.f};

  for (int kb = 0; kb < 16; ++kb){
    const uint4* ga = (const uint4*)(temb + (size_t)(m0 + srow)*1024 + kb*64 + shalf*32);
    const uint4* gb = (const uint4*)(wmid + (size_t)(n0 + srow)*1024 + kb*64 + shalf*32);
    uint4 va[4], vb[4];
    #pragma unroll
    for (int i = 0; i < 4; ++i){ va[i] = ga[i]; vb[i] = gb[i]; }
    #pragma unroll
    for (int i = 0; i < 4; ++i){
      *(uint4*)&Al[srow][shalf*32 + i*8] = va[i];
      *(uint4*)&Bl[srow][shalf*32 + i*8] = vb[i];
    }
    __syncthreads();
    #pragma unroll
    for (int kc = 0; kc < 2; ++kc){
      bf16x8_t af[4], bf[4];
      #pragma unroll
      for (int mt = 0; mt < 4; ++mt) af[mt] = *(const bf16x8_t*)&Al[wm*64 + mt*16 + ln][kc*32 + q*8];
      #pragma unroll
      for (int nt = 0; nt < 4; ++nt) bf[nt] = *(const bf16x8_t*)&Bl[wn*64 + nt*16 + ln][kc*32 + q*8];
      #pragma unroll
      for (int mt = 0; mt < 4; ++mt)
        #pragma unroll
        for (int nt = 0; nt < 4; ++nt)
          acc[mt][nt] = __builtin_amdgcn_mfma_f32_16x16x32_bf16(af[mt], bf[nt], acc[mt][nt], 0, 0, 0);
    }
    __syncthreads();
  }
  #pragma unroll
  for (int mt = 0; mt < 4; ++mt)
    #pragma unroll
    for (int nt = 0; nt < 4; ++nt)
      #pragma unroll
      for (int r = 0; r < 4; ++r){
        int Mr = m0 + wm*64 + mt*16 + q*4 + r;    // C/D: col=lane&15, row=quad*4+reg (m89-verified)
        int Nc = n0 + wn*64 + nt*16 + ln;
        G[(size_t)Mr*2048 + Nc] = f2b(acc[mt][nt][r]);
      }
}

// ---------------- lstmk: persistent recurrence (R6: coalesced poll-on-data) ----------------
// 128 blocks = 8 row-groups (16 rows) x 16 col-groups (32 units). blockIdx = g*8 + rr.
__launch_bounds__(256)
__global__ void lstmk(const float* __restrict__ x, const float* __restrict__ c0,
                      const int* __restrict__ lengths,
                      const uint16_t* __restrict__ whh_b, const uint16_t* __restrict__ G,
                      const float* __restrict__ wc0, const float* __restrict__ wc1,
                      const float* __restrict__ bc,
                      uint16_t* __restrict__ h_hist, float* __restrict__ hfin){
  __shared__ __align__(16) uint16_t h_l[2][16][552]; // cols 0..511 h, 512..519 xf, 520..543 zeros

  const int tid = threadIdx.x;
  const int bid = blockIdx.x;
  const int rr = bid & 7;         // row-group
  const int g  = bid >> 3;        // col-group
  const int k0 = g*32;
  const int sp = rr >> 2;         // segment of this row-group
  const int w = tid >> 6, lane = tid & 63;
  const int q = lane >> 4, ln = lane & 15;
  const int u8 = ln & 7, gh = ln >> 3;          // unit-in-octet, gate-half
  const int unit = k0 + w*8 + u8;               // this lane's hidden unit
  const int gl0 = gh*512 + unit;                // tile0 gate rows: i (gh=0), f (gh=1)
  const int gl1 = (2 + gh)*512 + unit;          // tile1 gate rows: g (gh=0), o (gh=1)

  // W_hh B-fragments resident in VGPRs/AGPRs, remapped N-tiles.
  bf16x8_t barr0[16], barr1[16];
  #pragma unroll
  for (int kc = 0; kc < 16; ++kc){
    barr0[kc] = *(const bf16x8_t*)(whh_b + (size_t)gl0*512 + kc*32 + q*8);
    barr1[kc] = *(const bf16x8_t*)(whh_b + (size_t)gl1*512 + kc*32 + q*8);
  }
  // K-extension B-fragments (xf @ Wc): rows k=512+q*8+j; only q==0 carries Wc, others zero.
  bf16x8_t e0f[2], e1f[2];
  #pragma unroll
  for (int nsI = 0; nsI < 2; ++nsI){
    bf16x8_t v0 = {0,0,0,0,0,0,0,0}, v1 = {0,0,0,0,0,0,0,0};
    if (q == 0){
      const float* wcs = nsI ? wc1 : wc0;
      #pragma unroll
      for (int j = 0; j < 8; ++j){
        ((uint16_t*)&v0)[j] = f2b(wcs[gl0*8 + j]);
        ((uint16_t*)&v1)[j] = f2b(wcs[gl1*8 + j]);
      }
    }
    e0f[nsI] = v0; e1f[nsI] = v1;
  }
  // biases per lane (per ns)
  float bc0v[2] = { bc[gl0], bc[2048 + gl0] };
  float bc1v[2] = { bc[gl1], bc[2048 + gl1] };

  // per-lane row ownership (C-layout rows q*4+r), cell state for ln<8 lanes
  int   bmr[4], lenr[4];
  float cst[4];
  #pragma unroll
  for (int r = 0; r < 4; ++r){
    int row = rr*16 + q*4 + r;
    bmr[r]  = row & 63;
    lenr[r] = lengths[bmr[r]];
    cst[r]  = c0[(size_t)bmr[r]*512 + unit];
  }

  // h staging map (R6 coalesced): thread -> (row hm, u64 word set {j + 16*i}, stride 128B)
  const int hm = tid >> 4, j = tid & 15;
  // xf staging map (tid<128): (row xm, col xc)
  const int xm = tid >> 3, xc = tid & 7;
  const int xb = (rr*16 + xm) & 63;

  // zero the K-extension tail (cols 520..543), both buffers (NaN-in-stale-LDS guard)
  for (int idx = tid; idx < 2*16*32; idx += 256)
    h_l[idx >> 9][(idx >> 5) & 15][520 + (idx & 31)] = 0;

  for (int t = 0; t < 128; ++t){
    const int qidx = sp*128 + t;
    const int ntm = qidx >> 1;     // source timestep (reshape interleave)
    const int ns  = qidx & 1;      // embedding branch

    // --- early independent loads: G slice (C-layout, cached) + xf source ---
    uint16_t g0r[4], g1r[4];
    #pragma unroll
    for (int r = 0; r < 4; ++r){
      size_t grow = (size_t)(bmr[r]*128 + ntm)*2048;
      g0r[r] = G[grow + gl0];
      g1r[r] = G[grow + gl1];
    }
    float xv = 0.f;
    if (tid < 128){
      if (ns == 0)      xv = x[(size_t)(xb*128 + ntm)*16 + 2 + xc];
      else if (xc < 6)  xv = x[(size_t)(xb*128 + ntm)*16 + 10 + xc];
    }

    // --- poll-on-data (coalesced): words j+16*i; per instruction, lanes cover 128
    //     contiguous bytes per row -> line-granular LLC requests ---
    {
      unsigned long long* hp = (unsigned long long*)
          (h_hist + ((size_t)t*128 + rr*16 + hm)*512);
      unsigned long long hv[8];
      while (true){
        bool ok = true;
        #pragma unroll
        for (int i = 0; i < 8; ++i){
          hv[i] = __hip_atomic_load(&hp[j + 16*i], __ATOMIC_RELAXED, __HIP_MEMORY_SCOPE_AGENT);
          ok &= ((uint32_t)hv[i] != SENT) & ((uint32_t)(hv[i] >> 32) != SENT);
        }
        if (ok) break;
        __builtin_amdgcn_s_sleep(1);
      }
      #pragma unroll
      for (int i = 0; i < 8; ++i)
        *(unsigned long long*)&h_l[t & 1][hm][(j + 16*i)*4] = hv[i];
    }
    if (tid < 128) h_l[t & 1][xm][512 + xc] = f2b(xv);
    __syncthreads();   // the only barrier per step (stage -> MFMA read)

    // --- gates = G + bias + [h|xf] @ [Whh|Wc]^T  (17 kc chunks) ---
    f32x4_t acc0, acc1;
    {
      float b0 = ns ? bc0v[1] : bc0v[0];
      float b1 = ns ? bc1v[1] : bc1v[0];
      #pragma unroll
      for (int r = 0; r < 4; ++r){ acc0[r] = bf2f(g0r[r]) + b0; acc1[r] = bf2f(g1r[r]) + b1; }
    }
    #pragma unroll
    for (int kc = 0; kc < 16; ++kc){
      bf16x8_t a = *(const bf16x8_t*)&h_l[t & 1][ln][kc*32 + q*8];
      acc0 = __builtin_amdgcn_mfma_f32_16x16x32_bf16(a, barr0[kc], acc0, 0, 0, 0);
      acc1 = __builtin_amdgcn_mfma_f32_16x16x32_bf16(a, barr1[kc], acc1, 0, 0, 0);
    }
    {
      bf16x8_t a = *(const bf16x8_t*)&h_l[t & 1][ln][512 + q*8];
      acc0 = __builtin_amdgcn_mfma_f32_16x16x32_bf16(a, ns ? e0f[1] : e0f[0], acc0, 0, 0, 0);
      acc1 = __builtin_amdgcn_mfma_f32_16x16x32_bf16(a, ns ? e1f[1] : e1f[0], acc1, 0, 0, 0);
    }

    // --- register gate exchange: lane ln has (i,g) for gh=0, (f,o) for gh=1 ---
    float pf[4], po[4];
    #pragma unroll
    for (int r = 0; r < 4; ++r){
      pf[r] = __shfl_xor(acc0[r], 8);
      po[r] = __shfl_xor(acc1[r], 8);
    }
    if (ln < 8){
      uint32_t hb[4]; float hF[4];
      #pragma unroll
      for (int r = 0; r < 4; ++r){
        float ig = acc0[r], fg = pf[r], gg = acc1[r], og = po[r];
        cst[r] = sigm(fg)*cst[r] + sigm(ig)*tanh_(gg);
        float h = sigm(og)*tanh_(cst[r]);
        hF[r] = h; hb[r] = (uint32_t)f2b(h);
      }
      #pragma unroll
      for (int r = 0; r < 4; ++r){
        uint32_t ph = (uint32_t)__shfl_xor((int)hb[r], 1);
        if (!(ln & 1)){
          uint32_t packed = hb[r] | (ph << 16);
          if (packed == SENT) packed ^= 1u;   // 1-ulp-at-3e-13 guard vs sentinel collision
          uint32_t* hp = (uint32_t*)(h_hist + ((size_t)(t+1)*128 + rr*16 + q*4 + r)*512 + unit);
          __hip_atomic_store(hp, packed, __ATOMIC_RELAXED, __HIP_MEMORY_SCOPE_AGENT);
        }
        if (t == lenr[r] - 1)
          hfin[(size_t)bmr[r]*1024 + sp*512 + unit] = hF[r];
      }
    }
    // no flag, no drain: the data is the flag.
  }
}

// ---------------- outk: out = sigmoid(hfin @ W_o^T + b_o) ----------------
__global__ void outk(const float* __restrict__ hfin, const float* __restrict__ W_o,
                     const float* __restrict__ b_o, float* __restrict__ out){
  __shared__ float hl[1024];
  __shared__ float red[16][17];
  const int b = blockIdx.x, tid = threadIdx.x;
  #pragma unroll
  for (int i = 0; i < 4; ++i) hl[tid + i*256] = hfin[(size_t)b*1024 + tid + i*256];
  __syncthreads();
  const int o = tid >> 4, j0 = tid & 15;
  float s = 0.f;
  if (o < 14){
    for (int j = j0; j < 1024; j += 16) s += hl[j]*W_o[(size_t)o*1024 + j];
  }
  red[o][j0] = s;
  __syncthreads();
  if (tid < 14){
    float tot = b_o[tid];
    #pragma unroll
    for (int i = 0; i < 16; ++i) tot += red[tid][i];
    out[b*14 + tid] = 1.0f/(1.0f + __expf(-tot));
  }
}

extern "C" void kernel_launch(void* const* d_in, const int* in_sizes, int n_in,
                              void* d_out, int out_size, void* d_ws, size_t ws_size,
                              hipStream_t stream){
  const float* x     = (const float*)d_in[0];
  const int*   lens  = (const int*)  d_in[1];
  const float* h0    = (const float*)d_in[2];
  const float* c0    = (const float*)d_in[3];
  const float* W_is0 = (const float*)d_in[4];
  const float* b_is0 = (const float*)d_in[5];
  const float* W_is1 = (const float*)d_in[6];
  const float* b_is1 = (const float*)d_in[7];
  const float* W_ih  = (const float*)d_in[8];
  const float* W_hh  = (const float*)d_in[9];
  const float* b_ih  = (const float*)d_in[10];
  const float* b_hh  = (const float*)d_in[11];
  const float* W_o   = (const float*)d_in[12];
  const float* b_o   = (const float*)d_in[13];
  float* out = (float*)d_out;

  char* ws = (char*)d_ws;   // needs ~74 MB
  uint16_t* G      = (uint16_t*)(ws + OFF_G);
  uint16_t* temb   = (uint16_t*)(ws + OFF_TEMB);
  uint16_t* h_hist = (uint16_t*)(ws + OFF_HH);
  uint16_t* whh_b  = (uint16_t*)(ws + OFF_WHH);
  uint16_t* wmid_b = (uint16_t*)(ws + OFF_WMID);
  float* wc0  = (float*)(ws + OFF_WC0);
  float* wc1  = (float*)(ws + OFF_WC1);
  float* bc   = (float*)(ws + OFF_BC);
  float* hfin = (float*)(ws + OFF_HFIN);

  hipLaunchKernelGGL(prep1, dim3(2048), dim3(256), 0, stream,
                     W_ih, W_hh, W_is0, b_is0, W_is1, b_is1, b_ih, b_hh,
                     whh_b, wmid_b, wc0, wc1, bc);
  hipLaunchKernelGGL(prep2, dim3(16512), dim3(256), 0, stream, h0, h_hist);
  hipLaunchKernelGGL(tembk, dim3(8192), dim3(256), 0, stream, x, temb);
  hipLaunchKernelGGL(gemmB, dim3(64, 16), dim3(256), 0, stream, temb, wmid_b, G);
  hipLaunchKernelGGL(lstmk, dim3(128), dim3(256), 0, stream,
                     x, c0, lens, whh_b, G, wc0, wc1, bc, h_hist, hfin);
  hipLaunchKernelGGL(outk, dim3(64), dim3(256), 0, stream, hfin, W_o, b_o, out);
}